// Round 13
// baseline (430.982 us; speedup 1.0000x reference)
//
#include <hip/hip_runtime.h>
#include <stdint.h>
#include <math.h>

typedef float f32x4 __attribute__((ext_vector_type(4)));
typedef __bf16 bf16x8_t __attribute__((ext_vector_type(8)));
typedef unsigned short us8 __attribute__((ext_vector_type(8)));
typedef unsigned short us4 __attribute__((ext_vector_type(4)));
typedef unsigned int u32;

__device__ __forceinline__ unsigned short f2bf(float f) {
  union { float f; uint32_t u; } v; v.f = f;
  uint32_t u = v.u;
  uint32_t r = (u + 0x7fffu + ((u >> 16) & 1u)) >> 16;
  return (unsigned short)r;
}
__device__ __forceinline__ float bf2f(unsigned short h) {
  union { uint32_t u; float f; } v; v.u = ((uint32_t)h) << 16;
  return v.f;
}
__device__ __forceinline__ f32x4 mfma16(us8 a, us8 b, f32x4 c) {
  return __builtin_amdgcn_mfma_f32_16x16x32_bf16(
      __builtin_bit_cast(bf16x8_t, a), __builtin_bit_cast(bf16x8_t, b), c, 0, 0, 0);
}
__device__ __forceinline__ void gl16(const void* g, void* l) {
  __builtin_amdgcn_global_load_lds(
      (const __attribute__((address_space(1))) u32*)g,
      (__attribute__((address_space(3))) u32*)l, 16, 0, 0);
}

// ================= memory plan =================
// d_out: fb bf16 [32768][1024] @0 (gemm_f out, gemm_o in; dead before ln2)
//        xb bf16 [32768][1024] @67108864 (x cast; dead after gemm_o)
//        out f32 [32768][1024] @0 (ln2, overwrites fb/xb); new_values @134217728
// d_ws:
//   wfb   bf16 [1024][1152] @0          B' = [Wf_top^T ; VWf^T]
//   shW   bf16 [1024][1024] @2359296    Wf_bot^T first, then WgT=(diag(g)Wo)^T
//   klw1  bf16 [256][1024]  @4456448
//   w2t   bf16 [128][128]   @4980736
//   valB  bf16 [128][1024]  @5013504
//   vg    f32 [1024]        @5275648
//   cb    f32 [1024]        @5279744    (= ln1b@Wo + bo)
//   stats f32 [32768][2]    @5283840    (mu, rs per row)
//   part  f32 [32768][32]   @5545984    (16 strips x {sum,sumsq})
//   attn  bf16 [32768][128] @9740288    (8MB) dead after gemm_f
//   ww    bf16 [32768][128] @18128896   (8MB) dead after wv
//   lg    f32 [32768][256]  @26517504   (32MB) dead after smx
//   partials f32 [32][131072] @26517504 (16MB, aliases lg) dead after red
//   tprime bf16 [32768][1024] @26517504 (64MB, aliases lg/partials)
//   end 93,626,368 B

// ---------------- tiled transpose+cast (optional source-row scale) ----------
__global__ __launch_bounds__(256) void k_tr(
    const float* __restrict__ src, unsigned short* __restrict__ dst,
    int R, int C, int dstride, const float* __restrict__ sc)
{
  __shared__ unsigned short X[64][68];
  int tile = blockIdx.x;
  int tpr = C >> 6;
  int tr = tile / tpr, tc = tile % tpr;
  int t = threadIdx.x;
  int r = t >> 2, c0 = (t & 3) * 16;
  float s = sc ? sc[tr * 64 + r] : 1.f;
  const float* sp = src + (size_t)(tr * 64 + r) * C + tc * 64 + c0;
  #pragma unroll
  for (int q = 0; q < 4; ++q) {
    f32x4 v = *(const f32x4*)(sp + q * 4);
    us4 o;
    #pragma unroll
    for (int e = 0; e < 4; ++e) o[e] = f2bf(v[e] * s);
    *(us4*)&X[r][c0 + q * 4] = o;
  }
  __syncthreads();
  int o = t >> 2, k0 = (t & 3) * 16;
  us8 w0, w1;
  #pragma unroll
  for (int e = 0; e < 8; ++e) { w0[e] = X[k0 + e][o]; w1[e] = X[k0 + 8 + e][o]; }
  unsigned short* dp = dst + (size_t)(tc * 64 + o) * dstride + tr * 64 + k0;
  *(us8*)dp = w0;
  *(us8*)(dp + 8) = w1;
}

// ---------------- small prep: keys/values cast ----------------
__global__ __launch_bounds__(256) void k_prep_small(
    const float* __restrict__ keys, const float* __restrict__ values,
    unsigned short* __restrict__ klw1, unsigned short* __restrict__ valB)
{
  int i = blockIdx.x * 256 + threadIdx.x;
  if (i < 131072) { klw1[i] = f2bf(keys[i]); return; }
  i -= 131072;
  valB[i] = f2bf(values[i]);
}

// ---------------- vg = ln1g@Wo ; cb = ln1b@Wo + bo ----------------
__global__ __launch_bounds__(256) void k_gemv(
    const float* __restrict__ Wo, const float* __restrict__ g,
    const float* __restrict__ b, const float* __restrict__ bo,
    float* __restrict__ vg, float* __restrict__ cb)
{
  int o = blockIdx.x * 256 + threadIdx.x;
  float sg = 0.f, sb = 0.f;
  #pragma unroll 8
  for (int k = 0; k < 1024; ++k) {
    float w = Wo[(size_t)k * 1024 + o];
    sg += g[k] * w;
    sb += b[k] * w;
  }
  vg[o] = sg;
  cb[o] = sb + bo[o];
}

// ---------------- cast x f32 -> xb bf16 ----------------
__global__ __launch_bounds__(256) void k_castx(
    const float* __restrict__ x, unsigned short* __restrict__ xb)
{
  size_t idx = ((size_t)blockIdx.x * 256 + threadIdx.x) * 8;
  f32x4 v0 = *(const f32x4*)(x + idx);
  f32x4 v1 = *(const f32x4*)(x + idx + 4);
  us8 o;
  #pragma unroll
  for (int e = 0; e < 4; ++e) { o[e] = f2bf(v0[e]); o[e + 4] = f2bf(v1[e]); }
  *(us8*)(xb + idx) = o;
}

// ---- MTx256 tile GEMM, BK=64, 512 thr, dbuf glds, counted vmcnt ----
// EPI 2: plain f32 store (logits)
// EPI 4: bf16 store TRANSPOSED into wfb cols 1024+ (VWf)
// EPI 5: affine-LN epilogue: v = rs*acc - mu*rs*vg[col] + cb[col] + resid(bf16)
// EPI 6: bf16 store + bias + per-strip stats partials (gemm_f)
template<int KTOT, int MT, int NTILES, int EPI, int KSPLIT = KTOT>
__global__ __launch_bounds__(512, 2) void k_gemm(
    const unsigned short* __restrict__ A, int astride,
    const unsigned short* __restrict__ A2, int astride2,
    const unsigned short* __restrict__ B,
    const float* __restrict__ bias,
    unsigned short* __restrict__ outB, float* __restrict__ outF,
    int ostride, int ocol,
    const unsigned short* __restrict__ residB,
    const float* __restrict__ stats, const float* __restrict__ vg,
    const float* __restrict__ cb, float* __restrict__ part)
{
  constexpr int NT = KTOT / 64;
  constexpr int AHW = MT * 64;
  constexpr int BUFHW = AHW + 16384;
  constexpr int AJ = MT / 64;
  constexpr int IFR = MT / 32;
  __shared__ __align__(16) unsigned short L[2 * BUFHW];

  int t = threadIdx.x;
  int bid = blockIdx.x;
  int logical;
  if (gridDim.x & 7) {
    logical = bid;
  } else {
    int cpx = gridDim.x >> 3;
    logical = (bid & 7) * cpx + (bid >> 3);       // XCD-contiguous
  }
  int m0 = (logical / NTILES) * MT, n0 = (logical % NTILES) * 256;

  int srow = t >> 3;
  int gslot = (t & 7) ^ (srow & 7);

  int w = t >> 6, l = t & 63, g = l >> 4, lc = l & 15;
  int wm = w >> 2, wn = w & 3;

  f32x4 acc[IFR][4] = {};

  auto stage = [&](int p, int kt) {
    int koff = kt * 64;
    const unsigned short* Ap = A; int astr = astride;
    if constexpr (KSPLIT < KTOT) {
      if (koff >= KSPLIT) { Ap = A2; astr = astride2; koff -= KSPLIT; }
    }
    int offa = koff + gslot * 8;
    int offb = kt * 64 + gslot * 8;
    #pragma unroll
    for (int j = 0; j < AJ; ++j)
      gl16(Ap + (size_t)(m0 + j * 64 + srow) * astr + offa,
           L + p * BUFHW + (j * 64 + srow) * 64 + (t & 7) * 8);
    #pragma unroll
    for (int j = 0; j < 4; ++j)
      gl16(B + (size_t)(n0 + j * 64 + srow) * KTOT + offb,
           L + p * BUFHW + AHW + (j * 64 + srow) * 64 + (t & 7) * 8);
  };

  stage(0, 0);
  if (NT > 1) stage(1, 1);

  for (int kt = 0; kt < NT; ++kt) {
    int p = kt & 1;
    if (kt + 1 < NT) {
      if constexpr (AJ + 4 == 6) asm volatile("s_waitcnt vmcnt(6)" ::: "memory");
      else                       asm volatile("s_waitcnt vmcnt(8)" ::: "memory");
    } else {
      asm volatile("s_waitcnt vmcnt(0)" ::: "memory");
    }
    __builtin_amdgcn_s_barrier();

    const unsigned short* Ab = L + p * BUFHW;
    const unsigned short* Bb = L + p * BUFHW + AHW;
    #pragma unroll
    for (int ks = 0; ks < 2; ++ks) {
      us8 av[IFR], bv[4];
      #pragma unroll
      for (int i = 0; i < IFR; ++i) {
        int row = wm * (MT / 2) + i * 16 + lc;
        av[i] = *(const us8*)(Ab + row * 64 + (((ks * 4 + g) ^ (lc & 7)) * 8));
      }
      #pragma unroll
      for (int j = 0; j < 4; ++j) {
        int row = wn * 64 + j * 16 + lc;
        bv[j] = *(const us8*)(Bb + row * 64 + (((ks * 4 + g) ^ (lc & 7)) * 8));
      }
      __builtin_amdgcn_s_setprio(1);
      #pragma unroll
      for (int i = 0; i < IFR; ++i)
        #pragma unroll
        for (int j = 0; j < 4; ++j)
          acc[i][j] = mfma16(av[i], bv[j], acc[i][j]);
      __builtin_amdgcn_s_setprio(0);
    }
    __builtin_amdgcn_s_barrier();
    if (kt + 2 < NT) stage(p, kt + 2);
  }

  float bv4[4], vg4[4], cb4[4];
  if constexpr (EPI == 6) {
    #pragma unroll
    for (int jn = 0; jn < 4; ++jn) bv4[jn] = bias[n0 + wn * 64 + jn * 16 + lc];
  }
  if constexpr (EPI == 5) {
    #pragma unroll
    for (int jn = 0; jn < 4; ++jn) {
      int col = n0 + wn * 64 + jn * 16 + lc;
      vg4[jn] = vg[col];
      cb4[jn] = cb[col];
    }
  }
  #pragma unroll
  for (int i = 0; i < IFR; ++i) {
    #pragma unroll
    for (int jj = 0; jj < 4; ++jj) {
      int row = m0 + wm * (MT / 2) + i * 16 + g * 4 + jj;
      float mu = 0.f, rs = 0.f;
      if constexpr (EPI == 5) { mu = stats[row * 2]; rs = stats[row * 2 + 1]; }
      float ssum = 0.f, ssq = 0.f;
      #pragma unroll
      for (int jn = 0; jn < 4; ++jn) {
        int col = n0 + wn * 64 + jn * 16 + lc;
        float v = acc[i][jn][jj];
        if constexpr (EPI == 6) v += bv4[jn];
        if constexpr (EPI == 5)
          v = rs * v - mu * rs * vg4[jn] + cb4[jn] + bf2f(residB[(size_t)row * 1024 + col]);
        if constexpr (EPI == 4) {
          outB[(size_t)col * 1152 + 1024 + row] = f2bf(v);
        } else {
          size_t oa = (size_t)row * ostride + ocol + col;
          if constexpr (EPI == 5 || EPI == 6) outB[oa] = f2bf(v);
          else                                outF[oa] = v;
        }
        if constexpr (EPI == 6) { ssum += v; ssq += v * v; }
      }
      if constexpr (EPI == 6) {
        #pragma unroll
        for (int msk = 1; msk < 16; msk <<= 1) {
          ssum += __shfl_xor(ssum, msk); ssq += __shfl_xor(ssq, msk);
        }
        if (lc == 0) {
          int strip = (n0 >> 6) + wn;
          part[(size_t)row * 32 + strip * 2]     = ssum;
          part[(size_t)row * 32 + strip * 2 + 1] = ssq;
        }
      }
    }
  }
}

// ---------------- fold 16 strip-partials -> (mu, rs) per row ----------------
__global__ __launch_bounds__(256) void k_statsred(
    const float* __restrict__ part, float* __restrict__ stats)
{
  int row = blockIdx.x * 256 + threadIdx.x;
  const float* p = part + (size_t)row * 32;
  float S = 0.f, Q = 0.f;
  #pragma unroll
  for (int i = 0; i < 16; ++i) { S += p[2 * i]; Q += p[2 * i + 1]; }
  float mu = S * (1.f / 1024.f);
  float rs = rsqrtf(Q * (1.f / 1024.f) - mu * mu + 1e-5f);
  stats[row * 2] = mu;
  stats[row * 2 + 1] = rs;
}

// ---------------- softmax + gelu + h@W2 -> attn, ww ----------------
__global__ __launch_bounds__(256) void k_smx(
    const float* __restrict__ lg, const float* __restrict__ b1,
    const float* __restrict__ b2, const float* __restrict__ temp,
    const unsigned short* __restrict__ w2t,
    unsigned short* __restrict__ attn, unsigned short* __restrict__ ww)
{
  __shared__ float lgs[16][260];
  __shared__ unsigned short hl[16][136];
  int t = threadIdx.x;
  int row0 = blockIdx.x * 16;

  {
    int r = t >> 4, c0 = (t & 15) * 16;
    const float* p = lg + (size_t)(row0 + r) * 256 + c0;
    #pragma unroll
    for (int q = 0; q < 4; ++q)
      *(f32x4*)&lgs[r][c0 + q * 4] = *(const f32x4*)(p + q * 4);
  }
  __syncthreads();

  {
    int r = t >> 4, sub = t & 15;
    float invt = 1.f / fmaxf(temp[0], 1e-6f);
    float vals[8]; float m = -3.4e38f;
    #pragma unroll
    for (int i = 0; i < 8; ++i) { vals[i] = lgs[r][sub * 8 + i]; m = fmaxf(m, vals[i]); }
    m = fmaxf(m, __shfl_xor(m, 1)); m = fmaxf(m, __shfl_xor(m, 2));
    m = fmaxf(m, __shfl_xor(m, 4)); m = fmaxf(m, __shfl_xor(m, 8));
    float ev[8]; float s = 0.f;
    #pragma unroll
    for (int i = 0; i < 8; ++i) { ev[i] = __expf((vals[i] - m) * invt); s += ev[i]; }
    s += __shfl_xor(s, 1); s += __shfl_xor(s, 2);
    s += __shfl_xor(s, 4); s += __shfl_xor(s, 8);
    float rinv = 1.f / s;
    us8 av;
    #pragma unroll
    for (int i = 0; i < 8; ++i) av[i] = f2bf(ev[i] * rinv);
    *(us8*)(attn + (size_t)(row0 + r) * 128 + sub * 8) = av;
    #pragma unroll
    for (int i = 0; i < 8; ++i) {
      float v = lgs[r][128 + sub * 8 + i] + b1[sub * 8 + i];
      v = 0.5f * v * (1.f + erff(v * 0.70710678118654752f));
      hl[r][sub * 8 + i] = f2bf(v);
    }
  }
  __syncthreads();

  int w = t >> 6, l = t & 63, g = l >> 4, lc = l & 15;
  int q2 = w * 2;
  f32x4 acc[2] = {};
  #pragma unroll
  for (int ks = 0; ks < 4; ++ks) {
    us8 a = *(const us8*)&hl[lc][ks * 32 + g * 8];
    #pragma unroll
    for (int i = 0; i < 2; ++i) {
      us8 b = *(const us8*)(w2t + (size_t)((q2 + i) * 16 + lc) * 128 + ks * 32 + g * 8);
      acc[i] = mfma16(a, b, acc[i]);
    }
  }
  #pragma unroll
  for (int i = 0; i < 2; ++i) {
    int col = (q2 + i) * 16 + lc;
    float bb = b2[col];
    #pragma unroll
    for (int j = 0; j < 4; ++j) {
      int r = row0 + g * 4 + j;
      float v = acc[i][j] + bb;
      v = 1.f / (1.f + __expf(-v));
      ww[(size_t)r * 128 + col] = f2bf(v);
    }
  }
}

// ---------------- ww^T @ x (32 chunks x 8 d-tiles) ----------------
__global__ __launch_bounds__(256) void k_wv(
    const unsigned short* __restrict__ xb, const unsigned short* __restrict__ ww,
    float* __restrict__ partials)
{
  __shared__ unsigned short wwT[128][40];
  __shared__ unsigned short xT[128][40];
  int t = threadIdx.x;
  int chunk = blockIdx.x >> 3;
  int dt0 = (blockIdx.x & 7) * 128;
  int w = t >> 6, l = t & 63, g = l >> 4, lc = l & 15;
  f32x4 acc[2][8] = {};
  int nn = t >> 3, e0 = (t & 7) * 16;

  for (int ks = 0; ks < 32; ++ks) {
    int n0 = chunk * 1024 + ks * 32;
    __syncthreads();
    {
      us8 v0 = *(const us8*)(ww + (size_t)(n0 + nn) * 128 + e0);
      us8 v1 = *(const us8*)(ww + (size_t)(n0 + nn) * 128 + e0 + 8);
      #pragma unroll
      for (int i = 0; i < 8; ++i) { wwT[e0 + i][nn] = v0[i]; wwT[e0 + 8 + i][nn] = v1[i]; }
      const unsigned short* xp = xb + (size_t)(n0 + nn) * 1024 + dt0 + e0;
      us8 x0 = *(const us8*)xp;
      us8 x1 = *(const us8*)(xp + 8);
      #pragma unroll
      for (int i = 0; i < 8; ++i) { xT[e0 + i][nn] = x0[i]; xT[e0 + 8 + i][nn] = x1[i]; }
    }
    __syncthreads();
    us8 bfr[8];
    #pragma unroll
    for (int i = 0; i < 8; ++i) bfr[i] = *(const us8*)&xT[i * 16 + lc][g * 8];
    #pragma unroll
    for (int st = 0; st < 2; ++st) {
      us8 a = *(const us8*)&wwT[(w * 2 + st) * 16 + lc][g * 8];
      #pragma unroll
      for (int i = 0; i < 8; ++i) acc[st][i] = mfma16(a, bfr[i], acc[st][i]);
    }
  }
  float* p = partials + (size_t)chunk * 131072;
  #pragma unroll
  for (int st = 0; st < 2; ++st)
    #pragma unroll
    for (int i = 0; i < 8; ++i)
      #pragma unroll
      for (int j = 0; j < 4; ++j) {
        int s = (w * 2 + st) * 16 + g * 4 + j;
        p[s * 1024 + dt0 + i * 16 + lc] = acc[st][i][j];
      }
}

__global__ __launch_bounds__(256) void k_red(
    const float* __restrict__ values, const float* __restrict__ partials,
    float* __restrict__ outv)
{
  int i = blockIdx.x * 256 + threadIdx.x;
  float s = 0.f;
  #pragma unroll
  for (int c = 0; c < 32; ++c) s += partials[(size_t)c * 131072 + i];
  outv[i] = values[i] + 0.1f * s;
}

// ------- LN2: t'' bf16 (already includes +x) ; stats in-wave ; write f32 ----
__global__ __launch_bounds__(256) void k_ln2(
    const unsigned short* __restrict__ tp,
    const float* __restrict__ g, const float* __restrict__ b,
    float* __restrict__ out)
{
  int w = threadIdx.x >> 6, l = threadIdx.x & 63;
  int row = blockIdx.x * 4 + w;
  size_t base = (size_t)row * 1024 + l * 16;
  us8 t0 = *(const us8*)(tp + base);
  us8 t1 = *(const us8*)(tp + base + 8);
  float vf[16];
  #pragma unroll
  for (int e = 0; e < 8; ++e) { vf[e] = bf2f(t0[e]); vf[e + 8] = bf2f(t1[e]); }
  float s = 0.f, sq = 0.f;
  #pragma unroll
  for (int e = 0; e < 16; ++e) { s += vf[e]; sq += vf[e] * vf[e]; }
  #pragma unroll
  for (int msk = 1; msk < 64; msk <<= 1) {
    s += __shfl_xor(s, msk); sq += __shfl_xor(sq, msk);
  }
  float mu = s * (1.f / 1024.f);
  float rs = rsqrtf(sq * (1.f / 1024.f) - mu * mu + 1e-5f);
  #pragma unroll
  for (int q = 0; q < 4; ++q) {
    f32x4 gv = *(const f32x4*)(g + l * 16 + q * 4);
    f32x4 bv = *(const f32x4*)(b + l * 16 + q * 4);
    f32x4 o;
    #pragma unroll
    for (int e = 0; e < 4; ++e)
      o[e] = (vf[q * 4 + e] - mu) * rs * gv[e] + bv[e];
    *(f32x4*)(out + base + q * 4) = o;
  }
}

extern "C" void kernel_launch(void* const* d_in, const int* in_sizes, int n_in,
                              void* d_out, int out_size, void* d_ws, size_t ws_size,
                              hipStream_t stream) {
  const float* x      = (const float*)d_in[0];
  const float* keys   = (const float*)d_in[1];
  const float* values = (const float*)d_in[2];
  const float* temp   = (const float*)d_in[3];
  const float* W1     = (const float*)d_in[4];
  const float* b1     = (const float*)d_in[5];
  const float* W2     = (const float*)d_in[6];
  const float* b2     = (const float*)d_in[7];
  const float* Wf     = (const float*)d_in[8];
  const float* bfp    = (const float*)d_in[9];
  const float* ln1g   = (const float*)d_in[10];
  const float* ln1b   = (const float*)d_in[11];
  const float* Wo     = (const float*)d_in[12];
  const float* bo     = (const float*)d_in[13];
  const float* ln2g   = (const float*)d_in[14];
  const float* ln2b   = (const float*)d_in[15];

  char* ws = (char*)d_ws;
  unsigned short* wfb   = (unsigned short*)(ws + 0);
  unsigned short* shW   = (unsigned short*)(ws + 2359296);
  unsigned short* klw1  = (unsigned short*)(ws + 4456448);
  unsigned short* w2t   = (unsigned short*)(ws + 4980736);
  unsigned short* valB  = (unsigned short*)(ws + 5013504);
  float* vg             = (float*)(ws + 5275648);
  float* cb             = (float*)(ws + 5279744);
  float* stats          = (float*)(ws + 5283840);
  float* part           = (float*)(ws + 5545984);
  unsigned short* attn  = (unsigned short*)(ws + 9740288);
  unsigned short* ww    = (unsigned short*)(ws + 18128896);
  float* lg             = (float*)(ws + 26517504);
  float* partials       = (float*)(ws + 26517504);
  unsigned short* tprime = (unsigned short*)(ws + 26517504);

  unsigned short* fb    = (unsigned short*)d_out;                       // [0,64MB)
  unsigned short* xb    = (unsigned short*)((char*)d_out + 67108864);   // [64,128MB)
  float* out            = (float*)d_out;
  float* newvals        = (float*)((char*)d_out + 134217728);

  // --- prep ---
  k_tr<<<256, 256, 0, stream>>>(Wf, wfb, 1024, 1024, 1152, nullptr);           // Wf_top^T
  k_tr<<<256, 256, 0, stream>>>(Wf + 1048576, shW, 1024, 1024, 1024, nullptr); // Wf_bot^T
  k_tr<<<32, 256, 0, stream>>>(W1, klw1 + 131072, 1024, 128, 1024, nullptr);
  k_tr<<<4, 256, 0, stream>>>(W2, w2t, 128, 128, 128, nullptr);
  k_prep_small<<<1024, 256, 0, stream>>>(keys, values, klw1, valB);
  k_castx<<<16384, 256, 0, stream>>>(x, xb);

  // VWf = values @ Wf_bot -> wfb cols [1024,1152) (transposed store)
  k_gemm<1024, 128, 4, 4><<<4, 512, 0, stream>>>(
      valB, 1024, nullptr, 0, shW, nullptr, wfb, nullptr, 0, 0,
      nullptr, nullptr, nullptr, nullptr, nullptr);
  // shW free -> WgT = (diag(ln1g) @ Wo)^T ; and vg/cb vectors
  k_tr<<<256, 256, 0, stream>>>(Wo, shW, 1024, 1024, 1024, ln1g);
  k_gemv<<<4, 256, 0, stream>>>(Wo, ln1g, ln1b, bo, vg, cb);

  // logits = x @ [keys;W1^T]^T
  k_gemm<1024, 128, 1, 2><<<256, 512, 0, stream>>>(
      xb, 1024, nullptr, 0, klw1, nullptr, nullptr, lg, 256, 0,
      nullptr, nullptr, nullptr, nullptr, nullptr);
  k_smx<<<2048, 256, 0, stream>>>(lg, b1, b2, temp, w2t, attn, ww);

  k_wv<<<256, 256, 0, stream>>>(xb, ww, partials);
  k_red<<<512, 256, 0, stream>>>(values, partials, newvals);

  // fused = [x|attn] @ [Wf_top^T;VWf^T]^T + bf  (+ per-strip stats partials)
  k_gemm<1152, 256, 4, 6, 1024><<<512, 512, 0, stream>>>(
      xb, 1024, attn, 128, wfb, bfp, fb, nullptr, 1024, 0,
      nullptr, nullptr, nullptr, nullptr, part);
  k_statsred<<<128, 256, 0, stream>>>(part, stats);

  // t'' = rs*(f@Wg) - mu*rs*vg + cb + x (bf16) ; ln2 does final LN only
  k_gemm<1024, 256, 4, 5><<<512, 512, 0, stream>>>(
      fb, 1024, nullptr, 0, shW, nullptr, tprime, nullptr, 1024, 0,
      xb, stats, vg, cb, nullptr);
  k_ln2<<<8192, 256, 0, stream>>>(tprime, ln2g, ln2b, out);
}

// Round 14
// 388.096 us; speedup vs baseline: 1.1105x; 1.1105x over previous
//
#include <hip/hip_runtime.h>
#include <stdint.h>
#include <math.h>

typedef float f32x4 __attribute__((ext_vector_type(4)));
typedef __bf16 bf16x8_t __attribute__((ext_vector_type(8)));
typedef unsigned short us8 __attribute__((ext_vector_type(8)));
typedef unsigned short us4 __attribute__((ext_vector_type(4)));
typedef unsigned int u32;

__device__ __forceinline__ unsigned short f2bf(float f) {
  union { float f; uint32_t u; } v; v.f = f;
  uint32_t u = v.u;
  uint32_t r = (u + 0x7fffu + ((u >> 16) & 1u)) >> 16;
  return (unsigned short)r;
}
__device__ __forceinline__ float bf2f(unsigned short h) {
  union { uint32_t u; float f; } v; v.u = ((uint32_t)h) << 16;
  return v.f;
}
__device__ __forceinline__ f32x4 mfma16(us8 a, us8 b, f32x4 c) {
  return __builtin_amdgcn_mfma_f32_16x16x32_bf16(
      __builtin_bit_cast(bf16x8_t, a), __builtin_bit_cast(bf16x8_t, b), c, 0, 0, 0);
}
__device__ __forceinline__ void gl16(const void* g, void* l) {
  __builtin_amdgcn_global_load_lds(
      (const __attribute__((address_space(1))) u32*)g,
      (__attribute__((address_space(3))) u32*)l, 16, 0, 0);
}

// ================= memory plan (R12 layout) =================
// d_out: fb bf16 [32768][1024] @0 ; xb bf16 [32768][1024] @67108864 ;
//        out f32 @0 (ln2, overwrites fb/xb) ; new_values @134217728
// d_ws:
//   wfb  bf16 [1024][1152] @0          B' = [Wf_top^T ; VWf^T]
//   shW  bf16 [1024][1024] @2359296    Wf_bot^T first, Wo^T later
//   klw1 bf16 [256][1024]  @4456448
//   w2t  bf16 [128][128]   @4980736
//   valB bf16 [128][1024]  @5013504
//   attn bf16 [32768][128] @5275648    (8MB) dead after gemm_f
//   ww   bf16 [32768][128] @13664256   (8MB) dead after wv
//   lg   f32 [32768][256]  @22052864   (32MB) dead after smx
//   partials f32 [32][131072] @22052864 (16MB alias) dead after red
//   tprime bf16 [32768][1024] @22052864 (64MB alias)  -> end 89,161,728

// ---------------- shared tile-transpose device helper ----------------
__device__ __forceinline__ void tr_tile(
    const float* __restrict__ src, unsigned short* __restrict__ dst,
    int C, int dstride, int tile, int t)
{
  __shared__ unsigned short X[64][68];
  int tpr = C >> 6;
  int tr = tile / tpr, tc = tile % tpr;
  int r = t >> 2, c0 = (t & 3) * 16;
  const float* sp = src + (size_t)(tr * 64 + r) * C + tc * 64 + c0;
  #pragma unroll
  for (int q = 0; q < 4; ++q) {
    f32x4 v = *(const f32x4*)(sp + q * 4);
    us4 o;
    #pragma unroll
    for (int e = 0; e < 4; ++e) o[e] = f2bf(v[e]);
    *(us4*)&X[r][c0 + q * 4] = o;
  }
  __syncthreads();
  int o = t >> 2, k0 = (t & 3) * 16;
  us8 w0, w1;
  #pragma unroll
  for (int e = 0; e < 8; ++e) { w0[e] = X[k0 + e][o]; w1[e] = X[k0 + 8 + e][o]; }
  unsigned short* dp = dst + (size_t)(tc * 64 + o) * dstride + (size_t)tr * 64 + k0;
  *(us8*)dp = w0;
  *(us8*)(dp + 8) = w1;
}

// ---------------- merged prep: all weight transposes + casts ----------------
__global__ __launch_bounds__(256) void k_prep_all(
    const float* __restrict__ Wf, const float* __restrict__ W1,
    const float* __restrict__ W2, const float* __restrict__ keys,
    const float* __restrict__ values,
    unsigned short* __restrict__ wfb, unsigned short* __restrict__ shW,
    unsigned short* __restrict__ klw1, unsigned short* __restrict__ w2t,
    unsigned short* __restrict__ valB)
{
  int b = blockIdx.x, t = threadIdx.x;
  if (b < 256)       { tr_tile(Wf,            wfb,            1024, 1152, b,       t); return; }
  if (b < 512)       { tr_tile(Wf + 1048576,  shW,            1024, 1024, b - 256, t); return; }
  if (b < 544)       { tr_tile(W1,            klw1 + 131072,  128,  1024, b - 512, t); return; }
  if (b < 548)       { tr_tile(W2,            w2t,            128,  128,  b - 544, t); return; }
  int i = (b - 548) * 256 + t;
  if (i < 131072) { klw1[i] = f2bf(keys[i]); return; }
  i -= 131072;
  valB[i] = f2bf(values[i]);
}

// ---------------- standalone transpose (Wo, after VWf gemm) ----------------
__global__ __launch_bounds__(256) void k_tr(
    const float* __restrict__ src, unsigned short* __restrict__ dst,
    int C, int dstride)
{
  tr_tile(src, dst, C, dstride, blockIdx.x, threadIdx.x);
}

// ---- MTx256 tile GEMM, BK=64, 512 thr, dbuf glds, counted vmcnt (R12) ----
// EPI 0: bf16 store + bias (gemm_f)
// EPI 4: bf16 store TRANSPOSED into wfb cols 1024+ (VWf)
// EPI 5: bf16 store + bias + bf16-resid (gemm_o: t'' = acc+bo+x)
template<int KTOT, int MT, int NTILES, int EPI, int KSPLIT = KTOT>
__global__ __launch_bounds__(512, 2) void k_gemm(
    const unsigned short* __restrict__ A, int astride,
    const unsigned short* __restrict__ A2, int astride2,
    const unsigned short* __restrict__ B,
    const float* __restrict__ bias,
    unsigned short* __restrict__ outB, float* __restrict__ outF,
    int ostride, int ocol,
    const unsigned short* __restrict__ residB)
{
  constexpr int NT = KTOT / 64;
  constexpr int AHW = MT * 64;
  constexpr int BUFHW = AHW + 16384;
  constexpr int AJ = MT / 64;
  constexpr int IFR = MT / 32;
  __shared__ __align__(16) unsigned short L[2 * BUFHW];

  int t = threadIdx.x;
  int bid = blockIdx.x;
  int logical;
  if (gridDim.x & 7) {
    logical = bid;
  } else {
    int cpx = gridDim.x >> 3;
    logical = (bid & 7) * cpx + (bid >> 3);       // XCD-contiguous
  }
  int m0 = (logical / NTILES) * MT, n0 = (logical % NTILES) * 256;

  int srow = t >> 3;
  int gslot = (t & 7) ^ (srow & 7);

  int w = t >> 6, l = t & 63, g = l >> 4, lc = l & 15;
  int wm = w >> 2, wn = w & 3;

  f32x4 acc[IFR][4] = {};

  auto stage = [&](int p, int kt) {
    int koff = kt * 64;
    const unsigned short* Ap = A; int astr = astride;
    if constexpr (KSPLIT < KTOT) {
      if (koff >= KSPLIT) { Ap = A2; astr = astride2; koff -= KSPLIT; }
    }
    int offa = koff + gslot * 8;
    int offb = kt * 64 + gslot * 8;
    #pragma unroll
    for (int j = 0; j < AJ; ++j)
      gl16(Ap + (size_t)(m0 + j * 64 + srow) * astr + offa,
           L + p * BUFHW + (j * 64 + srow) * 64 + (t & 7) * 8);
    #pragma unroll
    for (int j = 0; j < 4; ++j)
      gl16(B + (size_t)(n0 + j * 64 + srow) * KTOT + offb,
           L + p * BUFHW + AHW + (j * 64 + srow) * 64 + (t & 7) * 8);
  };

  stage(0, 0);
  if (NT > 1) stage(1, 1);

  for (int kt = 0; kt < NT; ++kt) {
    int p = kt & 1;
    if (kt + 1 < NT) {
      if constexpr (AJ + 4 == 6) asm volatile("s_waitcnt vmcnt(6)" ::: "memory");
      else                       asm volatile("s_waitcnt vmcnt(8)" ::: "memory");
    } else {
      asm volatile("s_waitcnt vmcnt(0)" ::: "memory");
    }
    __builtin_amdgcn_s_barrier();

    const unsigned short* Ab = L + p * BUFHW;
    const unsigned short* Bb = L + p * BUFHW + AHW;
    #pragma unroll
    for (int ks = 0; ks < 2; ++ks) {
      us8 av[IFR], bv[4];
      #pragma unroll
      for (int i = 0; i < IFR; ++i) {
        int row = wm * (MT / 2) + i * 16 + lc;
        av[i] = *(const us8*)(Ab + row * 64 + (((ks * 4 + g) ^ (lc & 7)) * 8));
      }
      #pragma unroll
      for (int j = 0; j < 4; ++j) {
        int row = wn * 64 + j * 16 + lc;
        bv[j] = *(const us8*)(Bb + row * 64 + (((ks * 4 + g) ^ (lc & 7)) * 8));
      }
      __builtin_amdgcn_s_setprio(1);
      #pragma unroll
      for (int i = 0; i < IFR; ++i)
        #pragma unroll
        for (int j = 0; j < 4; ++j)
          acc[i][j] = mfma16(av[i], bv[j], acc[i][j]);
      __builtin_amdgcn_s_setprio(0);
    }
    __builtin_amdgcn_s_barrier();
    if (kt + 2 < NT) stage(p, kt + 2);
  }

  float bv4[4];
  if constexpr (EPI == 0 || EPI == 5) {
    #pragma unroll
    for (int jn = 0; jn < 4; ++jn) bv4[jn] = bias[n0 + wn * 64 + jn * 16 + lc];
  }
  #pragma unroll
  for (int i = 0; i < IFR; ++i) {
    #pragma unroll
    for (int jj = 0; jj < 4; ++jj) {
      int row = m0 + wm * (MT / 2) + i * 16 + g * 4 + jj;
      #pragma unroll
      for (int jn = 0; jn < 4; ++jn) {
        int col = n0 + wn * 64 + jn * 16 + lc;
        float v = acc[i][jn][jj];
        if constexpr (EPI == 0 || EPI == 5) v += bv4[jn];
        if constexpr (EPI == 5) v += bf2f(residB[(size_t)row * 1024 + col]);
        if constexpr (EPI == 4) {
          outB[(size_t)col * 1152 + 1024 + row] = f2bf(v);
        } else {
          size_t oa = (size_t)row * ostride + ocol + col;
          if constexpr (EPI == 0 || EPI == 5) outB[oa] = f2bf(v);
          else                                outF[oa] = v;
        }
      }
    }
  }
}

// ======= fused castx + logits GEMM =======
// lg = bf16(x) @ klw1^T ; also writes xb = bf16(x).
// MT=64 rows/block, N=256, K=1024, 512 thr, 8 waves (2Mx4N), LDS 80KB,
// 2 blocks/CU. A reg-staged from f32 (swizzled ds_write), B via glds.
__global__ __launch_bounds__(512, 4) void k_logx(
    const float* __restrict__ x, const unsigned short* __restrict__ klw1,
    unsigned short* __restrict__ xb, float* __restrict__ lg)
{
  constexpr int NT = 16;
  __shared__ __align__(16) unsigned short Al[2][4096];
  __shared__ __align__(16) unsigned short Bl[2][16384];

  int t = threadIdx.x;
  int bid = blockIdx.x;
  int cpx = gridDim.x >> 3;
  int logical = (bid & 7) * cpx + (bid >> 3);
  int m0 = logical * 64;

  // A: thread t -> row r=t>>3, granule q=t&7 (8 bf16 = 16B)
  int ar = t >> 3, aq = t & 7;
  int adst = ar * 64 + ((aq ^ (ar & 7)) * 8);
  const float* axp = x + (size_t)(m0 + ar) * 1024 + aq * 8;
  unsigned short* xbp = xb + (size_t)(m0 + ar) * 1024 + aq * 8;

  // B: glds, 4 loads/thread
  int srow = t >> 3;
  int gslot = (t & 7) ^ (srow & 7);

  int w = t >> 6, l = t & 63, g = l >> 4, lc = l & 15;
  int wm = w >> 2, wn = w & 3;

  f32x4 acc[2][4] = {};
  f32x4 a0, a1;

  auto loadA = [&](int kt) {
    a0 = *(const f32x4*)(axp + kt * 64);
    a1 = *(const f32x4*)(axp + kt * 64 + 4);
  };
  auto stageB = [&](int p, int kt) {
    #pragma unroll
    for (int j = 0; j < 4; ++j)
      gl16(klw1 + (size_t)(j * 64 + srow) * 1024 + kt * 64 + gslot * 8,
           &Bl[p][(j * 64 + srow) * 64 + (t & 7) * 8]);
  };

  loadA(0);
  stageB(0, 0);

  for (int kt = 0; kt < NT; ++kt) {
    int cur = kt & 1;
    // cvt A(kt) -> bf16 ; write xb + LDS (swizzled slot)
    us8 av8;
    #pragma unroll
    for (int e = 0; e < 4; ++e) { av8[e] = f2bf(a0[e]); av8[e + 4] = f2bf(a1[e]); }
    *(us8*)(xbp + kt * 64) = av8;
    *(us8*)&Al[cur][adst] = av8;
    __syncthreads();                       // drains prev glds + makes ds_write visible
    if (kt + 1 < NT) {
      loadA(kt + 1);                       // long-latency, covered by MFMA below
      stageB(cur ^ 1, kt + 1);
    }
    #pragma unroll
    for (int ks = 0; ks < 2; ++ks) {
      us8 af[2], bf[4];
      #pragma unroll
      for (int i = 0; i < 2; ++i) {
        int row = wm * 32 + i * 16 + lc;
        af[i] = *(const us8*)&Al[cur][row * 64 + (((ks * 4 + g) ^ (lc & 7)) * 8)];
      }
      #pragma unroll
      for (int j = 0; j < 4; ++j) {
        int row = wn * 64 + j * 16 + lc;
        bf[j] = *(const us8*)&Bl[cur][row * 64 + (((ks * 4 + g) ^ (lc & 7)) * 8)];
      }
      #pragma unroll
      for (int i = 0; i < 2; ++i)
        #pragma unroll
        for (int j = 0; j < 4; ++j)
          acc[i][j] = mfma16(af[i], bf[j], acc[i][j]);
    }
    __syncthreads();                       // all waves done reading before next ds_write
  }

  #pragma unroll
  for (int i = 0; i < 2; ++i)
    #pragma unroll
    for (int jj = 0; jj < 4; ++jj) {
      int row = m0 + wm * 32 + i * 16 + g * 4 + jj;
      #pragma unroll
      for (int jn = 0; jn < 4; ++jn) {
        int col = wn * 64 + jn * 16 + lc;
        lg[(size_t)row * 256 + col] = acc[i][jn][jj];
      }
    }
}

// ---------------- softmax + gelu + h@W2 -> attn, ww ----------------
__global__ __launch_bounds__(256) void k_smx(
    const float* __restrict__ lg, const float* __restrict__ b1,
    const float* __restrict__ b2, const float* __restrict__ temp,
    const unsigned short* __restrict__ w2t,
    unsigned short* __restrict__ attn, unsigned short* __restrict__ ww)
{
  __shared__ float lgs[16][260];
  __shared__ unsigned short hl[16][136];
  int t = threadIdx.x;
  int row0 = blockIdx.x * 16;

  {
    int r = t >> 4, c0 = (t & 15) * 16;
    const float* p = lg + (size_t)(row0 + r) * 256 + c0;
    #pragma unroll
    for (int q = 0; q < 4; ++q)
      *(f32x4*)&lgs[r][c0 + q * 4] = *(const f32x4*)(p + q * 4);
  }
  __syncthreads();

  {
    int r = t >> 4, sub = t & 15;
    float invt = 1.f / fmaxf(temp[0], 1e-6f);
    float vals[8]; float m = -3.4e38f;
    #pragma unroll
    for (int i = 0; i < 8; ++i) { vals[i] = lgs[r][sub * 8 + i]; m = fmaxf(m, vals[i]); }
    m = fmaxf(m, __shfl_xor(m, 1)); m = fmaxf(m, __shfl_xor(m, 2));
    m = fmaxf(m, __shfl_xor(m, 4)); m = fmaxf(m, __shfl_xor(m, 8));
    float ev[8]; float s = 0.f;
    #pragma unroll
    for (int i = 0; i < 8; ++i) { ev[i] = __expf((vals[i] - m) * invt); s += ev[i]; }
    s += __shfl_xor(s, 1); s += __shfl_xor(s, 2);
    s += __shfl_xor(s, 4); s += __shfl_xor(s, 8);
    float rinv = 1.f / s;
    us8 av;
    #pragma unroll
    for (int i = 0; i < 8; ++i) av[i] = f2bf(ev[i] * rinv);
    *(us8*)(attn + (size_t)(row0 + r) * 128 + sub * 8) = av;
    #pragma unroll
    for (int i = 0; i < 8; ++i) {
      float v = lgs[r][128 + sub * 8 + i] + b1[sub * 8 + i];
      v = 0.5f * v * (1.f + erff(v * 0.70710678118654752f));
      hl[r][sub * 8 + i] = f2bf(v);
    }
  }
  __syncthreads();

  int w = t >> 6, l = t & 63, g = l >> 4, lc = l & 15;
  int q2 = w * 2;
  f32x4 acc[2] = {};
  #pragma unroll
  for (int ks = 0; ks < 4; ++ks) {
    us8 a = *(const us8*)&hl[lc][ks * 32 + g * 8];
    #pragma unroll
    for (int i = 0; i < 2; ++i) {
      us8 b = *(const us8*)(w2t + (size_t)((q2 + i) * 16 + lc) * 128 + ks * 32 + g * 8);
      acc[i] = mfma16(a, b, acc[i]);
    }
  }
  #pragma unroll
  for (int i = 0; i < 2; ++i) {
    int col = (q2 + i) * 16 + lc;
    float bb = b2[col];
    #pragma unroll
    for (int j = 0; j < 4; ++j) {
      int r = row0 + g * 4 + j;
      float v = acc[i][j] + bb;
      v = 1.f / (1.f + __expf(-v));
      ww[(size_t)r * 128 + col] = f2bf(v);
    }
  }
}

// ---------------- ww^T @ x (32 chunks x 8 d-tiles) ----------------
__global__ __launch_bounds__(256) void k_wv(
    const unsigned short* __restrict__ xb, const unsigned short* __restrict__ ww,
    float* __restrict__ partials)
{
  __shared__ unsigned short wwT[128][40];
  __shared__ unsigned short xT[128][40];
  int t = threadIdx.x;
  int chunk = blockIdx.x >> 3;
  int dt0 = (blockIdx.x & 7) * 128;
  int w = t >> 6, l = t & 63, g = l >> 4, lc = l & 15;
  f32x4 acc[2][8] = {};
  int nn = t >> 3, e0 = (t & 7) * 16;

  for (int ks = 0; ks < 32; ++ks) {
    int n0 = chunk * 1024 + ks * 32;
    __syncthreads();
    {
      us8 v0 = *(const us8*)(ww + (size_t)(n0 + nn) * 128 + e0);
      us8 v1 = *(const us8*)(ww + (size_t)(n0 + nn) * 128 + e0 + 8);
      #pragma unroll
      for (int i = 0; i < 8; ++i) { wwT[e0 + i][nn] = v0[i]; wwT[e0 + 8 + i][nn] = v1[i]; }
      const unsigned short* xp = xb + (size_t)(n0 + nn) * 1024 + dt0 + e0;
      us8 x0 = *(const us8*)xp;
      us8 x1 = *(const us8*)(xp + 8);
      #pragma unroll
      for (int i = 0; i < 8; ++i) { xT[e0 + i][nn] = x0[i]; xT[e0 + 8 + i][nn] = x1[i]; }
    }
    __syncthreads();
    us8 bfr[8];
    #pragma unroll
    for (int i = 0; i < 8; ++i) bfr[i] = *(const us8*)&xT[i * 16 + lc][g * 8];
    #pragma unroll
    for (int st = 0; st < 2; ++st) {
      us8 a = *(const us8*)&wwT[(w * 2 + st) * 16 + lc][g * 8];
      #pragma unroll
      for (int i = 0; i < 8; ++i) acc[st][i] = mfma16(a, bfr[i], acc[st][i]);
    }
  }
  float* p = partials + (size_t)chunk * 131072;
  #pragma unroll
  for (int st = 0; st < 2; ++st)
    #pragma unroll
    for (int i = 0; i < 8; ++i)
      #pragma unroll
      for (int j = 0; j < 4; ++j) {
        int s = (w * 2 + st) * 16 + g * 4 + j;
        p[s * 1024 + dt0 + i * 16 + lc] = acc[st][i][j];
      }
}

__global__ __launch_bounds__(256) void k_red(
    const float* __restrict__ values, const float* __restrict__ partials,
    float* __restrict__ outv)
{
  int i = blockIdx.x * 256 + threadIdx.x;
  float s = 0.f;
  #pragma unroll
  for (int c = 0; c < 32; ++c) s += partials[(size_t)c * 131072 + i];
  outv[i] = values[i] + 0.1f * s;
}

// ------------- LN1 in place on fb, self-computed stats (1 wave/row) --------
__global__ __launch_bounds__(256) void k_ln1(
    unsigned short* __restrict__ fb,
    const float* __restrict__ g, const float* __restrict__ b)
{
  int w = threadIdx.x >> 6, l = threadIdx.x & 63;
  int row = blockIdx.x * 4 + w;
  unsigned short* p = fb + (size_t)row * 1024 + l * 16;
  us8 v0 = *(const us8*)p;
  us8 v1 = *(const us8*)(p + 8);
  float vf[16];
  float s = 0.f, sq = 0.f;
  #pragma unroll
  for (int e = 0; e < 8; ++e) { vf[e] = bf2f(v0[e]); vf[e + 8] = bf2f(v1[e]); }
  #pragma unroll
  for (int e = 0; e < 16; ++e) { s += vf[e]; sq += vf[e] * vf[e]; }
  #pragma unroll
  for (int msk = 1; msk < 64; msk <<= 1) {
    s += __shfl_xor(s, msk); sq += __shfl_xor(sq, msk);
  }
  float mu = s * (1.f / 1024.f);
  float rs = rsqrtf(sq * (1.f / 1024.f) - mu * mu + 1e-5f);
  float gv[16], bv[16];
  #pragma unroll
  for (int q = 0; q < 4; ++q) {
    *(f32x4*)&gv[q * 4] = *(const f32x4*)(g + l * 16 + q * 4);
    *(f32x4*)&bv[q * 4] = *(const f32x4*)(b + l * 16 + q * 4);
  }
  us8 o0, o1;
  #pragma unroll
  for (int e = 0; e < 8; ++e) {
    o0[e] = f2bf((vf[e] - mu) * rs * gv[e] + bv[e]);
    o1[e] = f2bf((vf[e + 8] - mu) * rs * gv[e + 8] + bv[e + 8]);
  }
  *(us8*)p = o0;
  *(us8*)(p + 8) = o1;
}

// ------- LN2: t'' bf16 (already includes +x) ; stats in-wave ; write f32 ----
__global__ __launch_bounds__(256) void k_ln2(
    const unsigned short* __restrict__ tp,
    const float* __restrict__ g, const float* __restrict__ b,
    float* __restrict__ out)
{
  int w = threadIdx.x >> 6, l = threadIdx.x & 63;
  int row = blockIdx.x * 4 + w;
  size_t base = (size_t)row * 1024 + l * 16;
  us8 t0 = *(const us8*)(tp + base);
  us8 t1 = *(const us8*)(tp + base + 8);
  float vf[16];
  #pragma unroll
  for (int e = 0; e < 8; ++e) { vf[e] = bf2f(t0[e]); vf[e + 8] = bf2f(t1[e]); }
  float s = 0.f, sq = 0.f;
  #pragma unroll
  for (int e = 0; e < 16; ++e) { s += vf[e]; sq += vf[e] * vf[e]; }
  #pragma unroll
  for (int msk = 1; msk < 64; msk <<= 1) {
    s += __shfl_xor(s, msk); sq += __shfl_xor(sq, msk);
  }
  float mu = s * (1.f / 1024.f);
  float rs = rsqrtf(sq * (1.f / 1024.f) - mu * mu + 1e-5f);
  #pragma unroll
  for (int q = 0; q < 4; ++q) {
    f32x4 gv = *(const f32x4*)(g + l * 16 + q * 4);
    f32x4 bv = *(const f32x4*)(b + l * 16 + q * 4);
    f32x4 o;
    #pragma unroll
    for (int e = 0; e < 4; ++e)
      o[e] = (vf[q * 4 + e] - mu) * rs * gv[e] + bv[e];
    *(f32x4*)(out + base + q * 4) = o;
  }
}

extern "C" void kernel_launch(void* const* d_in, const int* in_sizes, int n_in,
                              void* d_out, int out_size, void* d_ws, size_t ws_size,
                              hipStream_t stream) {
  const float* x      = (const float*)d_in[0];
  const float* keys   = (const float*)d_in[1];
  const float* values = (const float*)d_in[2];
  const float* temp   = (const float*)d_in[3];
  const float* W1     = (const float*)d_in[4];
  const float* b1     = (const float*)d_in[5];
  const float* W2     = (const float*)d_in[6];
  const float* b2     = (const float*)d_in[7];
  const float* Wf     = (const float*)d_in[8];
  const float* bfp    = (const float*)d_in[9];
  const float* ln1g   = (const float*)d_in[10];
  const float* ln1b   = (const float*)d_in[11];
  const float* Wo     = (const float*)d_in[12];
  const float* bo     = (const float*)d_in[13];
  const float* ln2g   = (const float*)d_in[14];
  const float* ln2b   = (const float*)d_in[15];

  char* ws = (char*)d_ws;
  unsigned short* wfb   = (unsigned short*)(ws + 0);
  unsigned short* shW   = (unsigned short*)(ws + 2359296);
  unsigned short* klw1  = (unsigned short*)(ws + 4456448);
  unsigned short* w2t   = (unsigned short*)(ws + 4980736);
  unsigned short* valB  = (unsigned short*)(ws + 5013504);
  unsigned short* attn  = (unsigned short*)(ws + 5275648);
  unsigned short* ww    = (unsigned short*)(ws + 13664256);
  float* lg             = (float*)(ws + 22052864);
  float* partials       = (float*)(ws + 22052864);
  unsigned short* tprime = (unsigned short*)(ws + 22052864);

  unsigned short* fb    = (unsigned short*)d_out;                       // [0,64MB)
  unsigned short* xb    = (unsigned short*)((char*)d_out + 67108864);   // [64,128MB)
  float* out            = (float*)d_out;
  float* newvals        = (float*)((char*)d_out + 134217728);

  // --- prep (one launch) ---
  k_prep_all<<<1572, 256, 0, stream>>>(Wf, W1, W2, keys, values,
                                       wfb, shW, klw1, w2t, valB);

  // VWf = values @ Wf_bot -> wfb cols [1024,1152) (transposed store)
  k_gemm<1024, 128, 4, 4><<<4, 512, 0, stream>>>(
      valB, 1024, nullptr, 0, shW, nullptr, wfb, nullptr, 0, 0, nullptr);
  // shW free -> Wo^T
  k_tr<<<256, 256, 0, stream>>>(Wo, shW, 1024, 1024);

  // fused: xb = bf16(x) ; lg = xb @ [keys;W1^T]^T
  k_logx<<<512, 512, 0, stream>>>(x, klw1, xb, lg);
  k_smx<<<2048, 256, 0, stream>>>(lg, b1, b2, temp, w2t, attn, ww);

  k_wv<<<256, 256, 0, stream>>>(xb, ww, partials);
  k_red<<<512, 256, 0, stream>>>(values, partials, newvals);

  // fused = [x|attn] @ [Wf_top^T;VWf^T]^T + bf   (A split at k=1024)
  k_gemm<1152, 256, 4, 0, 1024><<<512, 512, 0, stream>>>(
      xb, 1024, attn, 128, wfb, bfp, fb, nullptr, 1024, 0, nullptr);
  k_ln1<<<8192, 256, 0, stream>>>(fb, ln1g, ln1b);

  // t'' = LN1(f)@Wo + bo + x (bf16) ; ln2 does final LN only
  k_gemm<1024, 256, 4, 5><<<512, 512, 0, stream>>>(
      fb, 1024, nullptr, 0, shW, bo, tprime, nullptr, 1024, 0, xb);
  k_ln2<<<8192, 256, 0, stream>>>(tprime, ln2g, ln2b, out);
}

// Round 15
// 368.542 us; speedup vs baseline: 1.1694x; 1.0531x over previous
//
#include <hip/hip_runtime.h>
#include <stdint.h>
#include <math.h>

typedef float f32x4 __attribute__((ext_vector_type(4)));
typedef __bf16 bf16x8_t __attribute__((ext_vector_type(8)));
typedef unsigned short us8 __attribute__((ext_vector_type(8)));
typedef unsigned short us4 __attribute__((ext_vector_type(4)));
typedef unsigned int u32;

__device__ __forceinline__ unsigned short f2bf(float f) {
  union { float f; uint32_t u; } v; v.f = f;
  uint32_t u = v.u;
  uint32_t r = (u + 0x7fffu + ((u >> 16) & 1u)) >> 16;
  return (unsigned short)r;
}
__device__ __forceinline__ float bf2f(unsigned short h) {
  union { uint32_t u; float f; } v; v.u = ((uint32_t)h) << 16;
  return v.f;
}
__device__ __forceinline__ f32x4 mfma16(us8 a, us8 b, f32x4 c) {
  return __builtin_amdgcn_mfma_f32_16x16x32_bf16(
      __builtin_bit_cast(bf16x8_t, a), __builtin_bit_cast(bf16x8_t, b), c, 0, 0, 0);
}
__device__ __forceinline__ void gl16(const void* g, void* l) {
  __builtin_amdgcn_global_load_lds(
      (const __attribute__((address_space(1))) u32*)g,
      (__attribute__((address_space(3))) u32*)l, 16, 0, 0);
}

// ================= memory plan =================
// d_out: fb bf16 [32768][1024] @0 ; xb bf16 [32768][1024] @67108864 ;
//        out f32 @0 (ln2, overwrites fb/xb) ; new_values @134217728
// d_ws:
//   wfb  bf16 [1024][1152] @0          B' = [Wf_top^T ; VWf^T]
//   shW  bf16 [1024][1024] @2359296    Wf_bot^T (VWf gemm input)
//   woT  bf16 [1024][1024] @4456448    Wo^T
//   klw1 bf16 [256][1024]  @6553600
//   w2t  bf16 [128][128]   @7077888
//   valB bf16 [128][1024]  @7110656
//   attn bf16 [32768][128] @7372800    (8MB) dead after gemm_f
//   ww   bf16 [32768][128] @15761408   (8MB) dead after wv
//   partials f32 [32][131072] @24150016 (16MB) dead after red
//   tprime bf16 [32768][1024] @24150016 (64MB, aliases partials)
//   end 91,258,880

// ---------------- shared tile-transpose device helper ----------------
__device__ __forceinline__ void tr_tile(
    const float* __restrict__ src, unsigned short* __restrict__ dst,
    int C, int dstride, int tile, int t)
{
  __shared__ unsigned short X[64][68];
  int tpr = C >> 6;
  int tr = tile / tpr, tc = tile % tpr;
  int r = t >> 2, c0 = (t & 3) * 16;
  const float* sp = src + (size_t)(tr * 64 + r) * C + tc * 64 + c0;
  #pragma unroll
  for (int q = 0; q < 4; ++q) {
    f32x4 v = *(const f32x4*)(sp + q * 4);
    us4 o;
    #pragma unroll
    for (int e = 0; e < 4; ++e) o[e] = f2bf(v[e]);
    *(us4*)&X[r][c0 + q * 4] = o;
  }
  __syncthreads();
  int o = t >> 2, k0 = (t & 3) * 16;
  us8 w0, w1;
  #pragma unroll
  for (int e = 0; e < 8; ++e) { w0[e] = X[k0 + e][o]; w1[e] = X[k0 + 8 + e][o]; }
  unsigned short* dp = dst + (size_t)(tc * 64 + o) * dstride + (size_t)tr * 64 + k0;
  *(us8*)dp = w0;
  *(us8*)(dp + 8) = w1;
}

// ---------------- merged prep: all weight transposes + casts ----------------
__global__ __launch_bounds__(256) void k_prep_all(
    const float* __restrict__ Wf, const float* __restrict__ Wo,
    const float* __restrict__ W1, const float* __restrict__ W2,
    const float* __restrict__ keys, const float* __restrict__ values,
    unsigned short* __restrict__ wfb, unsigned short* __restrict__ shW,
    unsigned short* __restrict__ woT, unsigned short* __restrict__ klw1,
    unsigned short* __restrict__ w2t, unsigned short* __restrict__ valB)
{
  int b = blockIdx.x, t = threadIdx.x;
  if (b < 256)  { tr_tile(Wf,           wfb,           1024, 1152, b,       t); return; }
  if (b < 512)  { tr_tile(Wf + 1048576, shW,           1024, 1024, b - 256, t); return; }
  if (b < 768)  { tr_tile(Wo,           woT,           1024, 1024, b - 512, t); return; }
  if (b < 800)  { tr_tile(W1,           klw1 + 131072, 128,  1024, b - 768, t); return; }
  if (b < 804)  { tr_tile(W2,           w2t,           128,  128,  b - 800, t); return; }
  int i = (b - 804) * 256 + t;
  if (i < 131072) { klw1[i] = f2bf(keys[i]); return; }
  i -= 131072;
  valB[i] = f2bf(values[i]);
}

// ---- MTx256 tile GEMM, BK=64, 512 thr, dbuf glds, counted vmcnt ----
// EPI 0: bf16 store + bias (gemm_f)
// EPI 4: bf16 store TRANSPOSED into wfb cols 1024+ (VWf)
// EPI 5: bf16 store + bias + bf16-resid (gemm_o: t'' = acc+bo+x)
template<int KTOT, int MT, int NTILES, int EPI, int KSPLIT = KTOT>
__global__ __launch_bounds__(512, 2) void k_gemm(
    const unsigned short* __restrict__ A, int astride,
    const unsigned short* __restrict__ A2, int astride2,
    const unsigned short* __restrict__ B,
    const float* __restrict__ bias,
    unsigned short* __restrict__ outB, float* __restrict__ outF,
    int ostride, int ocol,
    const unsigned short* __restrict__ residB)
{
  constexpr int NT = KTOT / 64;
  constexpr int AHW = MT * 64;
  constexpr int BUFHW = AHW + 16384;
  constexpr int AJ = MT / 64;
  constexpr int IFR = MT / 32;
  __shared__ __align__(16) unsigned short L[2 * BUFHW];

  int t = threadIdx.x;
  int bid = blockIdx.x;
  int logical;
  if (gridDim.x & 7) {
    logical = bid;
  } else {
    int cpx = gridDim.x >> 3;
    logical = (bid & 7) * cpx + (bid >> 3);       // XCD-contiguous
  }
  int m0 = (logical / NTILES) * MT, n0 = (logical % NTILES) * 256;

  int srow = t >> 3;
  int gslot = (t & 7) ^ (srow & 7);

  int w = t >> 6, l = t & 63, g = l >> 4, lc = l & 15;
  int wm = w >> 2, wn = w & 3;

  f32x4 acc[IFR][4] = {};

  auto stage = [&](int p, int kt) {
    int koff = kt * 64;
    const unsigned short* Ap = A; int astr = astride;
    if constexpr (KSPLIT < KTOT) {
      if (koff >= KSPLIT) { Ap = A2; astr = astride2; koff -= KSPLIT; }
    }
    int offa = koff + gslot * 8;
    int offb = kt * 64 + gslot * 8;
    #pragma unroll
    for (int j = 0; j < AJ; ++j)
      gl16(Ap + (size_t)(m0 + j * 64 + srow) * astr + offa,
           L + p * BUFHW + (j * 64 + srow) * 64 + (t & 7) * 8);
    #pragma unroll
    for (int j = 0; j < 4; ++j)
      gl16(B + (size_t)(n0 + j * 64 + srow) * KTOT + offb,
           L + p * BUFHW + AHW + (j * 64 + srow) * 64 + (t & 7) * 8);
  };

  stage(0, 0);
  if (NT > 1) stage(1, 1);

  for (int kt = 0; kt < NT; ++kt) {
    int p = kt & 1;
    if (kt + 1 < NT) {
      if constexpr (AJ + 4 == 6) asm volatile("s_waitcnt vmcnt(6)" ::: "memory");
      else                       asm volatile("s_waitcnt vmcnt(8)" ::: "memory");
    } else {
      asm volatile("s_waitcnt vmcnt(0)" ::: "memory");
    }
    __builtin_amdgcn_s_barrier();

    const unsigned short* Ab = L + p * BUFHW;
    const unsigned short* Bb = L + p * BUFHW + AHW;
    #pragma unroll
    for (int ks = 0; ks < 2; ++ks) {
      us8 av[IFR], bv[4];
      #pragma unroll
      for (int i = 0; i < IFR; ++i) {
        int row = wm * (MT / 2) + i * 16 + lc;
        av[i] = *(const us8*)(Ab + row * 64 + (((ks * 4 + g) ^ (lc & 7)) * 8));
      }
      #pragma unroll
      for (int j = 0; j < 4; ++j) {
        int row = wn * 64 + j * 16 + lc;
        bv[j] = *(const us8*)(Bb + row * 64 + (((ks * 4 + g) ^ (lc & 7)) * 8));
      }
      __builtin_amdgcn_s_setprio(1);
      #pragma unroll
      for (int i = 0; i < IFR; ++i)
        #pragma unroll
        for (int j = 0; j < 4; ++j)
          acc[i][j] = mfma16(av[i], bv[j], acc[i][j]);
      __builtin_amdgcn_s_setprio(0);
    }
    __builtin_amdgcn_s_barrier();
    if (kt + 2 < NT) stage(p, kt + 2);
  }

  float bv4[4];
  if constexpr (EPI == 0 || EPI == 5) {
    #pragma unroll
    for (int jn = 0; jn < 4; ++jn) bv4[jn] = bias[n0 + wn * 64 + jn * 16 + lc];
  }
  #pragma unroll
  for (int i = 0; i < IFR; ++i) {
    #pragma unroll
    for (int jj = 0; jj < 4; ++jj) {
      int row = m0 + wm * (MT / 2) + i * 16 + g * 4 + jj;
      #pragma unroll
      for (int jn = 0; jn < 4; ++jn) {
        int col = n0 + wn * 64 + jn * 16 + lc;
        float v = acc[i][jn][jj];
        if constexpr (EPI == 0 || EPI == 5) v += bv4[jn];
        if constexpr (EPI == 5) v += bf2f(residB[(size_t)row * 1024 + col]);
        if constexpr (EPI == 4) {
          outB[(size_t)col * 1152 + 1024 + row] = f2bf(v);
        } else {
          size_t oa = (size_t)row * ostride + ocol + col;
          if constexpr (EPI == 0 || EPI == 5) outB[oa] = f2bf(v);
          else                                outF[oa] = v;
        }
      }
    }
  }
}

// ======= fused castx + logits GEMM + softmax + gelu + h@W2 =======
// Per 64-row block: lg = bf16(x)@klw1^T kept in acc (never to HBM);
// wn<2 waves: softmax -> attn ; wn>=2: gelu -> h (LDS) ; all: ww=sig(h@W2+b2).
// Also writes xb = bf16(x). LDS 80KB reused post-loop (rm/sm in Al, h in Bl).
__global__ __launch_bounds__(512, 4) void k_logx(
    const float* __restrict__ x, const unsigned short* __restrict__ klw1,
    const float* __restrict__ b1, const float* __restrict__ b2,
    const float* __restrict__ temp, const unsigned short* __restrict__ w2t,
    unsigned short* __restrict__ xb, unsigned short* __restrict__ attn,
    unsigned short* __restrict__ ww)
{
  constexpr int NT = 16;
  __shared__ __align__(16) char LR[81920];
  unsigned short* Al = (unsigned short*)LR;            // [2][4096]
  unsigned short* Bl = (unsigned short*)(LR + 16384);  // [2][16384]

  int t = threadIdx.x;
  int bid = blockIdx.x;
  int cpx = gridDim.x >> 3;
  int logical = (bid & 7) * cpx + (bid >> 3);
  int m0 = logical * 64;

  int ar = t >> 3, aq = t & 7;
  int adst = ar * 64 + ((aq ^ (ar & 7)) * 8);
  const float* axp = x + (size_t)(m0 + ar) * 1024 + aq * 8;
  unsigned short* xbp = xb + (size_t)(m0 + ar) * 1024 + aq * 8;

  int srow = t >> 3;
  int gslot = (t & 7) ^ (srow & 7);

  int w = t >> 6, l = t & 63, g = l >> 4, lc = l & 15;
  int wm = w >> 2, wn = w & 3;

  f32x4 acc[2][4] = {};
  f32x4 a0, a1;

  auto loadA = [&](int kt) {
    a0 = *(const f32x4*)(axp + kt * 64);
    a1 = *(const f32x4*)(axp + kt * 64 + 4);
  };
  auto stageB = [&](int p, int kt) {
    #pragma unroll
    for (int j = 0; j < 4; ++j)
      gl16(klw1 + (size_t)(j * 64 + srow) * 1024 + kt * 64 + gslot * 8,
           &Bl[p * 16384 + (j * 64 + srow) * 64 + (t & 7) * 8]);
  };

  loadA(0);
  stageB(0, 0);

  for (int kt = 0; kt < NT; ++kt) {
    int cur = kt & 1;
    us8 av8;
    #pragma unroll
    for (int e = 0; e < 4; ++e) { av8[e] = f2bf(a0[e]); av8[e + 4] = f2bf(a1[e]); }
    *(us8*)(xbp + kt * 64) = av8;
    *(us8*)&Al[cur * 4096 + adst] = av8;
    __syncthreads();
    if (kt + 1 < NT) {
      loadA(kt + 1);
      stageB(cur ^ 1, kt + 1);
    }
    #pragma unroll
    for (int ks = 0; ks < 2; ++ks) {
      us8 af[2], bf[4];
      #pragma unroll
      for (int i = 0; i < 2; ++i) {
        int row = wm * 32 + i * 16 + lc;
        af[i] = *(const us8*)&Al[cur * 4096 + row * 64 + (((ks * 4 + g) ^ (lc & 7)) * 8)];
      }
      #pragma unroll
      for (int j = 0; j < 4; ++j) {
        int row = wn * 64 + j * 16 + lc;
        bf[j] = *(const us8*)&Bl[cur * 16384 + row * 64 + (((ks * 4 + g) ^ (lc & 7)) * 8)];
      }
      #pragma unroll
      for (int i = 0; i < 2; ++i)
        #pragma unroll
        for (int j = 0; j < 4; ++j)
          acc[i][j] = mfma16(af[i], bf[j], acc[i][j]);
    }
    __syncthreads();
  }

  // ---- fused epilogue: acc[i][jn][jj] = lg[row_l][col], row_l = wm*32+i*16+g*4+jj,
  // col = wn*64 + jn*16 + lc.  Al/Bl regions are dead -> reuse.
  float* rm = (float*)LR;              // [64][2] row max partials
  float* sm = (float*)(LR + 512);      // [64][2] row sum partials
  unsigned short* hb = (unsigned short*)(LR + 16384);  // h [64][128] swizzled
  float invt = 1.f / fmaxf(temp[0], 1e-6f);

  if (wn < 2) {
    // wave-partial row max over 64 cols
    #pragma unroll
    for (int i = 0; i < 2; ++i)
      #pragma unroll
      for (int jj = 0; jj < 4; ++jj) {
        float mx = fmaxf(fmaxf(acc[i][0][jj], acc[i][1][jj]),
                         fmaxf(acc[i][2][jj], acc[i][3][jj]));
        mx = fmaxf(mx, __shfl_xor(mx, 1)); mx = fmaxf(mx, __shfl_xor(mx, 2));
        mx = fmaxf(mx, __shfl_xor(mx, 4)); mx = fmaxf(mx, __shfl_xor(mx, 8));
        if (lc == 0) rm[(wm * 32 + i * 16 + g * 4 + jj) * 2 + wn] = mx;
      }
  } else {
    // gelu -> h into LDS (granule-XOR swizzle for conflict-free us8 reads)
    #pragma unroll
    for (int i = 0; i < 2; ++i)
      #pragma unroll
      for (int jj = 0; jj < 4; ++jj) {
        int r = wm * 32 + i * 16 + g * 4 + jj;
        #pragma unroll
        for (int jn = 0; jn < 4; ++jn) {
          int colh = (wn - 2) * 64 + jn * 16 + lc;
          float v = acc[i][jn][jj] + b1[colh];
          v = 0.5f * v * (1.f + erff(v * 0.70710678118654752f));
          hb[r * 128 + (((colh >> 3) ^ (r & 7)) * 8) + (colh & 7)] = f2bf(v);
        }
      }
  }
  __syncthreads();

  if (wn < 2) {
    #pragma unroll
    for (int i = 0; i < 2; ++i)
      #pragma unroll
      for (int jj = 0; jj < 4; ++jj) {
        int r = wm * 32 + i * 16 + g * 4 + jj;
        float m = fmaxf(rm[r * 2], rm[r * 2 + 1]);
        float s = 0.f;
        #pragma unroll
        for (int jn = 0; jn < 4; ++jn) {
          float e = __expf((acc[i][jn][jj] - m) * invt);
          acc[i][jn][jj] = e;
          s += e;
        }
        s += __shfl_xor(s, 1); s += __shfl_xor(s, 2);
        s += __shfl_xor(s, 4); s += __shfl_xor(s, 8);
        if (lc == 0) sm[r * 2 + wn] = s;
      }
  }
  __syncthreads();

  if (wn < 2) {
    #pragma unroll
    for (int i = 0; i < 2; ++i)
      #pragma unroll
      for (int jj = 0; jj < 4; ++jj) {
        int r = wm * 32 + i * 16 + g * 4 + jj;
        float rinv = 1.f / (sm[r * 2] + sm[r * 2 + 1]);
        #pragma unroll
        for (int jn = 0; jn < 4; ++jn) {
          int col = wn * 64 + jn * 16 + lc;
          attn[(size_t)(m0 + r) * 128 + col] = f2bf(acc[i][jn][jj] * rinv);
        }
      }
  }

  // ww = sigmoid(h @ W2^T + b2) : wave w -> rows band*16.., cols ch0..ch0+63
  {
    int band = w & 3, ch0 = (w >> 2) * 64;
    int arow = band * 16 + lc;
    f32x4 acc2[4] = {};
    #pragma unroll
    for (int ks = 0; ks < 4; ++ks) {
      us8 a = *(const us8*)&hb[arow * 128 + (((ks * 4 + g) ^ (arow & 7)) * 8)];
      #pragma unroll
      for (int jn = 0; jn < 4; ++jn) {
        us8 b = *(const us8*)(w2t + (size_t)(ch0 + jn * 16 + lc) * 128 + ks * 32 + g * 8);
        acc2[jn] = mfma16(a, b, acc2[jn]);
      }
    }
    #pragma unroll
    for (int jn = 0; jn < 4; ++jn) {
      int col = ch0 + jn * 16 + lc;
      float bb = b2[col];
      #pragma unroll
      for (int jj = 0; jj < 4; ++jj) {
        int r = band * 16 + g * 4 + jj;
        float v = acc2[jn][jj] + bb;
        v = 1.f / (1.f + __expf(-v));
        ww[(size_t)(m0 + r) * 128 + col] = f2bf(v);
      }
    }
  }
}

// ---------------- ww^T @ x (32 chunks x 8 d-tiles) ----------------
__global__ __launch_bounds__(256) void k_wv(
    const unsigned short* __restrict__ xb, const unsigned short* __restrict__ ww,
    float* __restrict__ partials)
{
  __shared__ unsigned short wwT[128][40];
  __shared__ unsigned short xT[128][40];
  int t = threadIdx.x;
  int chunk = blockIdx.x >> 3;
  int dt0 = (blockIdx.x & 7) * 128;
  int w = t >> 6, l = t & 63, g = l >> 4, lc = l & 15;
  f32x4 acc[2][8] = {};
  int nn = t >> 3, e0 = (t & 7) * 16;

  for (int ks = 0; ks < 32; ++ks) {
    int n0 = chunk * 1024 + ks * 32;
    __syncthreads();
    {
      us8 v0 = *(const us8*)(ww + (size_t)(n0 + nn) * 128 + e0);
      us8 v1 = *(const us8*)(ww + (size_t)(n0 + nn) * 128 + e0 + 8);
      #pragma unroll
      for (int i = 0; i < 8; ++i) { wwT[e0 + i][nn] = v0[i]; wwT[e0 + 8 + i][nn] = v1[i]; }
      const unsigned short* xp = xb + (size_t)(n0 + nn) * 1024 + dt0 + e0;
      us8 x0 = *(const us8*)xp;
      us8 x1 = *(const us8*)(xp + 8);
      #pragma unroll
      for (int i = 0; i < 8; ++i) { xT[e0 + i][nn] = x0[i]; xT[e0 + 8 + i][nn] = x1[i]; }
    }
    __syncthreads();
    us8 bfr[8];
    #pragma unroll
    for (int i = 0; i < 8; ++i) bfr[i] = *(const us8*)&xT[i * 16 + lc][g * 8];
    #pragma unroll
    for (int st = 0; st < 2; ++st) {
      us8 a = *(const us8*)&wwT[(w * 2 + st) * 16 + lc][g * 8];
      #pragma unroll
      for (int i = 0; i < 8; ++i) acc[st][i] = mfma16(a, bfr[i], acc[st][i]);
    }
  }
  float* p = partials + (size_t)chunk * 131072;
  #pragma unroll
  for (int st = 0; st < 2; ++st)
    #pragma unroll
    for (int i = 0; i < 8; ++i)
      #pragma unroll
      for (int j = 0; j < 4; ++j) {
        int s = (w * 2 + st) * 16 + g * 4 + j;
        p[s * 1024 + dt0 + i * 16 + lc] = acc[st][i][j];
      }
}

__global__ __launch_bounds__(256) void k_red(
    const float* __restrict__ values, const float* __restrict__ partials,
    float* __restrict__ outv)
{
  int i = blockIdx.x * 256 + threadIdx.x;
  float s = 0.f;
  #pragma unroll
  for (int c = 0; c < 32; ++c) s += partials[(size_t)c * 131072 + i];
  outv[i] = values[i] + 0.1f * s;
}

// ------------- LN1 in place on fb, self-computed stats (1 wave/row) --------
__global__ __launch_bounds__(256) void k_ln1(
    unsigned short* __restrict__ fb,
    const float* __restrict__ g, const float* __restrict__ b)
{
  int w = threadIdx.x >> 6, l = threadIdx.x & 63;
  int row = blockIdx.x * 4 + w;
  unsigned short* p = fb + (size_t)row * 1024 + l * 16;
  us8 v0 = *(const us8*)p;
  us8 v1 = *(const us8*)(p + 8);
  float vf[16];
  float s = 0.f, sq = 0.f;
  #pragma unroll
  for (int e = 0; e < 8; ++e) { vf[e] = bf2f(v0[e]); vf[e + 8] = bf2f(v1[e]); }
  #pragma unroll
  for (int e = 0; e < 16; ++e) { s += vf[e]; sq += vf[e] * vf[e]; }
  #pragma unroll
  for (int msk = 1; msk < 64; msk <<= 1) {
    s += __shfl_xor(s, msk); sq += __shfl_xor(sq, msk);
  }
  float mu = s * (1.f / 1024.f);
  float rs = rsqrtf(sq * (1.f / 1024.f) - mu * mu + 1e-5f);
  float gv[16], bv[16];
  #pragma unroll
  for (int q = 0; q < 4; ++q) {
    *(f32x4*)&gv[q * 4] = *(const f32x4*)(g + l * 16 + q * 4);
    *(f32x4*)&bv[q * 4] = *(const f32x4*)(b + l * 16 + q * 4);
  }
  us8 o0, o1;
  #pragma unroll
  for (int e = 0; e < 8; ++e) {
    o0[e] = f2bf((vf[e] - mu) * rs * gv[e] + bv[e]);
    o1[e] = f2bf((vf[e + 8] - mu) * rs * gv[e + 8] + bv[e + 8]);
  }
  *(us8*)p = o0;
  *(us8*)(p + 8) = o1;
}

// ------- LN2: t'' bf16 (already includes +x) ; stats in-wave ; write f32 ----
__global__ __launch_bounds__(256) void k_ln2(
    const unsigned short* __restrict__ tp,
    const float* __restrict__ g, const float* __restrict__ b,
    float* __restrict__ out)
{
  int w = threadIdx.x >> 6, l = threadIdx.x & 63;
  int row = blockIdx.x * 4 + w;
  size_t base = (size_t)row * 1024 + l * 16;
  us8 t0 = *(const us8*)(tp + base);
  us8 t1 = *(const us8*)(tp + base + 8);
  float vf[16];
  #pragma unroll
  for (int e = 0; e < 8; ++e) { vf[e] = bf2f(t0[e]); vf[e + 8] = bf2f(t1[e]); }
  float s = 0.f, sq = 0.f;
  #pragma unroll
  for (int e = 0; e < 16; ++e) { s += vf[e]; sq += vf[e] * vf[e]; }
  #pragma unroll
  for (int msk = 1; msk < 64; msk <<= 1) {
    s += __shfl_xor(s, msk); sq += __shfl_xor(sq, msk);
  }
  float mu = s * (1.f / 1024.f);
  float rs = rsqrtf(sq * (1.f / 1024.f) - mu * mu + 1e-5f);
  #pragma unroll
  for (int q = 0; q < 4; ++q) {
    f32x4 gv = *(const f32x4*)(g + l * 16 + q * 4);
    f32x4 bv = *(const f32x4*)(b + l * 16 + q * 4);
    f32x4 o;
    #pragma unroll
    for (int e = 0; e < 4; ++e)
      o[e] = (vf[q * 4 + e] - mu) * rs * gv[e] + bv[e];
    *(f32x4*)(out + base + q * 4) = o;
  }
}

extern "C" void kernel_launch(void* const* d_in, const int* in_sizes, int n_in,
                              void* d_out, int out_size, void* d_ws, size_t ws_size,
                              hipStream_t stream) {
  const float* x      = (const float*)d_in[0];
  const float* keys   = (const float*)d_in[1];
  const float* values = (const float*)d_in[2];
  const float* temp   = (const float*)d_in[3];
  const float* W1     = (const float*)d_in[4];
  const float* b1     = (const float*)d_in[5];
  const float* W2     = (const float*)d_in[6];
  const float* b2     = (const float*)d_in[7];
  const float* Wf     = (const float*)d_in[8];
  const float* bfp    = (const float*)d_in[9];
  const float* ln1g   = (const float*)d_in[10];
  const float* ln1b   = (const float*)d_in[11];
  const float* Wo     = (const float*)d_in[12];
  const float* bo     = (const float*)d_in[13];
  const float* ln2g   = (const float*)d_in[14];
  const float* ln2b   = (const float*)d_in[15];

  char* ws = (char*)d_ws;
  unsigned short* wfb   = (unsigned short*)(ws + 0);
  unsigned short* shW   = (unsigned short*)(ws + 2359296);
  unsigned short* woT   = (unsigned short*)(ws + 4456448);
  unsigned short* klw1  = (unsigned short*)(ws + 6553600);
  unsigned short* w2t   = (unsigned short*)(ws + 7077888);
  unsigned short* valB  = (unsigned short*)(ws + 7110656);
  unsigned short* attn  = (unsigned short*)(ws + 7372800);
  unsigned short* ww    = (unsigned short*)(ws + 15761408);
  float* partials       = (float*)(ws + 24150016);
  unsigned short* tprime = (unsigned short*)(ws + 24150016);  // after partials dead

  unsigned short* fb    = (unsigned short*)d_out;                       // [0,64MB)
  unsigned short* xb    = (unsigned short*)((char*)d_out + 67108864);   // [64,128MB)
  float* out            = (float*)d_out;
  float* newvals        = (float*)((char*)d_out + 134217728);

  // --- prep (one launch: all transposes + casts) ---
  k_prep_all<<<1828, 256, 0, stream>>>(Wf, Wo, W1, W2, keys, values,
                                       wfb, shW, woT, klw1, w2t, valB);

  // VWf = values @ Wf_bot -> wfb cols [1024,1152) (transposed store)
  k_gemm<1024, 128, 4, 4><<<4, 512, 0, stream>>>(
      valB, 1024, nullptr, 0, shW, nullptr, wfb, nullptr, 0, 0, nullptr);

  // fused: xb = bf16(x) ; softmax->attn ; gelu+W2 -> ww (lg stays on-chip)
  k_logx<<<512, 512, 0, stream>>>(x, klw1, b1, b2, temp, w2t, xb, attn, ww);

  k_wv<<<256, 256, 0, stream>>>(xb, ww, partials);
  k_red<<<512, 256, 0, stream>>>(values, partials, newvals);

  // fused = [x|attn] @ [Wf_top^T;VWf^T]^T + bf   (A split at k=1024)
  k_gemm<1152, 256, 4, 0, 1024><<<512, 512, 0, stream>>>(
      xb, 1024, attn, 128, wfb, bfp, fb, nullptr, 1024, 0, nullptr);
  k_ln1<<<8192, 256, 0, stream>>>(fb, ln1g, ln1b);

  // t'' = LN1(f)@Wo + bo + x (bf16) ; ln2 does final LN only
  k_gemm<1024, 256, 4, 5><<<512, 512, 0, stream>>>(
      fb, 1024, nullptr, 0, woT, bo, tprime, nullptr, 1024, 0, xb);
  k_ln2<<<8192, 256, 0, stream>>>(tprime, ln2g, ln2b, out);
}